// Round 9
// baseline (34.695 us; speedup 1.0000x reference)
//
#include <hip/hip_runtime.h>

typedef __attribute__((ext_vector_type(8))) __bf16 bf16x8;
typedef __attribute__((ext_vector_type(4))) __bf16 bf16x4;
typedef __attribute__((ext_vector_type(4))) float f32x4;

#define LDST 72   // LDS row stride in bf16 (64 + 8 pad -> 144 B, max 2-way conflict = free)

// Barrier that only drains this wave's LDS ops (lgkmcnt), NOT vmem stores.
// Safe with double-buffered LDS: reads hit buf[cur], writes hit buf[cur^1].
__device__ __forceinline__ void lds_barrier() {
    asm volatile("s_waitcnt lgkmcnt(0)" ::: "memory");
    __builtin_amdgcn_s_barrier();
    __builtin_amdgcn_sched_barrier(0);
}
// Full drain (stores too) — used once before the diagonal overwrite.
__device__ __forceinline__ void full_barrier() {
    asm volatile("s_waitcnt vmcnt(0) lgkmcnt(0)" ::: "memory");
    __builtin_amdgcn_s_barrier();
    __builtin_amdgcn_sched_barrier(0);
}

// One block = one 32-row strip x ALL columns of one batch. 512 threads = 8 waves;
// wave w owns 16 panel-cols of each 128-col tile. Grid: flat 512 blocks,
// batch = id & 7 (one batch per XCD for L2 panel reuse).
__global__ __launch_bounds__(512) void lap_strip_kernel(
    const float* __restrict__ X, float* __restrict__ out, int N)
{
    const int flat   = blockIdx.x;
    const int b      = flat & 7;
    const int strip0 = (flat >> 3) * 32;
    const int tid  = threadIdx.x;     // 0..511
    const int lane = tid & 63;
    const int w    = tid >> 6;        // wave 0..7
    const int t    = lane & 15;
    const int g    = lane >> 4;

    __shared__ __align__(16) unsigned short As[2][128 * LDST];  // col-panel double buffer
    __shared__ __align__(16) unsigned short Bs[32 * LDST];      // strip (loop-invariant)
    __shared__ float deg_part[8][32];

    const float* Xb   = X   + (size_t)b * N * 64;
    float*       outb = out + (size_t)b * N * N;

    // ---- stage strip rows: 32 x 64 fp32 -> bf16 (512 float4, one per thread) ----
    {
        const float4* src = reinterpret_cast<const float4*>(Xb + (size_t)strip0 * 64);
        int r = tid >> 4, q = tid & 15;
        float4 v = src[tid];
        bf16x4 h = {(__bf16)v.x, (__bf16)v.y, (__bf16)v.z, (__bf16)v.w};
        *reinterpret_cast<bf16x4*>(&Bs[r * LDST + q * 4]) = h;
    }

    // ---- stage col-panel 0 into As[0] (2048 float4 = 4 per thread) ----
    float4 pre[4];
    {
        const float4* src = reinterpret_cast<const float4*>(Xb);
#pragma unroll
        for (int it = 0; it < 4; ++it) pre[it] = src[tid + it * 512];
#pragma unroll
        for (int it = 0; it < 4; ++it) {
            int idx = tid + it * 512;
            int r = idx >> 4, q = idx & 15;
            float4 v = pre[it];
            bf16x4 h = {(__bf16)v.x, (__bf16)v.y, (__bf16)v.z, (__bf16)v.w};
            *reinterpret_cast<bf16x4*>(&As[0][r * LDST + q * 4]) = h;
        }
    }
    lds_barrier();

    // strip fragments are loop-invariant: load once
    bf16x8 bfrag[2][2];   // [ks][fj]
#pragma unroll
    for (int ks = 0; ks < 2; ++ks)
#pragma unroll
        for (int fj = 0; fj < 2; ++fj)
            bfrag[ks][fj] = *reinterpret_cast<const bf16x8*>(
                &Bs[(16 * fj + t) * LDST + ks * 32 + g * 8]);

    float rs[2] = {0.f, 0.f};
    int cur = 0;
    const int nct = N >> 7;            // 16 column tiles of 128
    const int diag_ct = strip0 >> 7;

    for (int ct = 0; ct < nct; ++ct) {
        // prefetch next panel into regs (hides HBM latency under MFMA+stores)
        if (ct + 1 < nct) {
            const float4* src = reinterpret_cast<const float4*>(Xb + (size_t)(ct + 1) * 128 * 64);
#pragma unroll
            for (int it = 0; it < 4; ++it) pre[it] = src[tid + it * 512];
        }

        // ---- compute: wave w -> panel rows [16w,16w+16) x strip 32 rows ----
        f32x4 acc[2] = {};   // [fj]
#pragma unroll
        for (int ks = 0; ks < 2; ++ks) {
            const int koff = ks * 32 + g * 8;
            bf16x8 a = *reinterpret_cast<const bf16x8*>(
                &As[cur][(16 * w + t) * LDST + koff]);
#pragma unroll
            for (int fj = 0; fj < 2; ++fj)
                acc[fj] = __builtin_amdgcn_mfma_f32_16x16x32_bf16(
                    a, bfrag[ks][fj], acc[fj], 0, 0, 0);
        }

        // ---- epilogue: |d| thresholds; transposed store -> contiguous f32x4 ----
        // Plain stores (no NT): L2 write-back merges the 8 waves' 64-B chunks
        // into full lines -> sequential full-line HBM evictions.
        const bool has_diag = (ct == diag_ct);
#pragma unroll
        for (int fj = 0; fj < 2; ++fj) {
            const int orow  = strip0 + 16 * fj + t;          // output row (strip side)
            const int ocol0 = ct * 128 + 16 * w + 4 * g;     // output col base (panel side)
            float wv[4];
#pragma unroll
            for (int r = 0; r < 4; ++r) {
                const float d = acc[fj][r];
                float wt = (fabsf(d) >= 0.97467943f) ? 1.0f
                         : ((fabsf(d) >= 0.70710678f) ? 0.5f : 0.0f);
                if (has_diag && (ocol0 + r == orow)) wt = 0.0f;
                rs[fj] += wt;
                wv[r] = -wt;
            }
            f32x4 st = {wv[0], wv[1], wv[2], wv[3]};
            *reinterpret_cast<f32x4*>(&outb[(size_t)orow * N + ocol0]) = st;
        }

        // ---- write next panel into the other buffer ----
        if (ct + 1 < nct) {
#pragma unroll
            for (int it = 0; it < 4; ++it) {
                int idx = tid + it * 512;
                int r = idx >> 4, q = idx & 15;
                float4 v = pre[it];
                bf16x4 h = {(__bf16)v.x, (__bf16)v.y, (__bf16)v.z, (__bf16)v.w};
                *reinterpret_cast<bf16x4*>(&As[cur ^ 1][r * LDST + q * 4]) = h;
            }
        }
        lds_barrier();
        cur ^= 1;
    }

    // ---- degree: reduce over g via shfl, across 8 waves via LDS ----
    rs[0] += __shfl_xor(rs[0], 16, 64); rs[0] += __shfl_xor(rs[0], 32, 64);
    rs[1] += __shfl_xor(rs[1], 16, 64); rs[1] += __shfl_xor(rs[1], 32, 64);
    if (g == 0) { deg_part[w][t] = rs[0]; deg_part[w][16 + t] = rs[1]; }
    full_barrier();   // drains vmem too: the diag-line store must land before overwrite
    if (tid < 32) {
        float d = 0.f;
#pragma unroll
        for (int ww = 0; ww < 8; ++ww) d += deg_part[ww][tid];
        const int rr = strip0 + tid;
        outb[(size_t)rr * N + rr] = d;   // diagonal = degree
    }
}

extern "C" void kernel_launch(void* const* d_in, const int* in_sizes, int n_in,
                              void* d_out, int out_size, void* d_ws, size_t ws_size,
                              hipStream_t stream) {
    const float* X = (const float*)d_in[0];
    float* out = (float*)d_out;

    const int B = 8;
    const int D = 64;
    const int N = in_sizes[0] / (B * D);   // 2048

    dim3 grid((N / 32) * B);               // 512 blocks, batch = id & 7
    lap_strip_kernel<<<grid, dim3(512), 0, stream>>>(X, out, N);
}

// Round 10
// 33.003 us; speedup vs baseline: 1.0513x; 1.0513x over previous
//
#include <hip/hip_runtime.h>

typedef __attribute__((ext_vector_type(8))) __bf16 bf16x8;
typedef __attribute__((ext_vector_type(4))) __bf16 bf16x4;
typedef __attribute__((ext_vector_type(4))) float f32x4;

#define LDST 68   // LDS row stride in bf16: 136 B, word-stride 34 -> rows skew 2 banks, b128 reads conflict-free

// Barrier draining only this wave's LDS ops (lgkmcnt), NOT vmem stores.
// Safe with double-buffered LDS: reads hit buf[cur], writes hit buf[cur^1].
__device__ __forceinline__ void lds_barrier() {
    asm volatile("s_waitcnt lgkmcnt(0)" ::: "memory");
    __builtin_amdgcn_s_barrier();
    __builtin_amdgcn_sched_barrier(0);
}
// Full drain (stores too) — used once before the diagonal overwrite.
__device__ __forceinline__ void full_barrier() {
    asm volatile("s_waitcnt vmcnt(0) lgkmcnt(0)" ::: "memory");
    __builtin_amdgcn_s_barrier();
    __builtin_amdgcn_sched_barrier(0);
}

// One block = one 32-row strip x ALL columns of one batch. 512 threads = 8 waves.
// Column tiles are 256 wide: each iteration writes 32 rows x 1 KB contiguous runs
// (HBM page-sized) instead of 512 B -> better write page locality.
// Grid: flat 512 blocks, batch = id & 7 (one batch per XCD for L2 panel reuse).
__global__ __launch_bounds__(512) void lap_strip_kernel(
    const float* __restrict__ X, float* __restrict__ out, int N)
{
    const int flat   = blockIdx.x;
    const int b      = flat & 7;
    const int strip0 = (flat >> 3) * 32;
    const int tid  = threadIdx.x;     // 0..511
    const int lane = tid & 63;
    const int w    = tid >> 6;        // wave 0..7
    const int t    = lane & 15;
    const int g    = lane >> 4;

    __shared__ __align__(16) unsigned short As[2][256 * LDST];  // 256-row col-panel, double-buffered (68 KB)
    __shared__ __align__(16) unsigned short Bs[32 * LDST];      // strip (loop-invariant)
    __shared__ float deg_part[8][32];

    const float* Xb   = X   + (size_t)b * N * 64;
    float*       outb = out + (size_t)b * N * N;

    // ---- stage strip rows: 32 x 64 fp32 -> bf16 (512 float4, one per thread) ----
    {
        const float4* src = reinterpret_cast<const float4*>(Xb + (size_t)strip0 * 64);
        int r = tid >> 4, q = tid & 15;
        float4 v = src[tid];
        bf16x4 h = {(__bf16)v.x, (__bf16)v.y, (__bf16)v.z, (__bf16)v.w};
        *reinterpret_cast<bf16x4*>(&Bs[r * LDST + q * 4]) = h;
    }

    // ---- stage col-panel 0 into As[0] (256 rows = 4096 float4 = 8 per thread) ----
    float4 pre[8];
    {
        const float4* src = reinterpret_cast<const float4*>(Xb);
#pragma unroll
        for (int it = 0; it < 8; ++it) pre[it] = src[tid + it * 512];
#pragma unroll
        for (int it = 0; it < 8; ++it) {
            int idx = tid + it * 512;
            int r = idx >> 4, q = idx & 15;
            float4 v = pre[it];
            bf16x4 h = {(__bf16)v.x, (__bf16)v.y, (__bf16)v.z, (__bf16)v.w};
            *reinterpret_cast<bf16x4*>(&As[0][r * LDST + q * 4]) = h;
        }
    }
    lds_barrier();

    // strip fragments are loop-invariant: load once
    bf16x8 bfrag[2][2];   // [ks][fj]
#pragma unroll
    for (int ks = 0; ks < 2; ++ks)
#pragma unroll
        for (int fj = 0; fj < 2; ++fj)
            bfrag[ks][fj] = *reinterpret_cast<const bf16x8*>(
                &Bs[(16 * fj + t) * LDST + ks * 32 + g * 8]);

    float rs[2] = {0.f, 0.f};
    int cur = 0;
    const int nct = N >> 8;            // 8 column tiles of 256
    const int diag_ct = strip0 >> 8;

    for (int ct = 0; ct < nct; ++ct) {
        // prefetch next 256-row panel into regs (hides HBM/L2 latency under MFMA+stores)
        if (ct + 1 < nct) {
            const float4* src = reinterpret_cast<const float4*>(Xb + (size_t)(ct + 1) * 256 * 64);
#pragma unroll
            for (int it = 0; it < 8; ++it) pre[it] = src[tid + it * 512];
        }

        // ---- compute: wave w -> panel rows [32w, 32w+32) x strip 32 rows ----
        f32x4 acc[2][2] = {};   // [fi][fj]
#pragma unroll
        for (int ks = 0; ks < 2; ++ks) {
            const int koff = ks * 32 + g * 8;
            bf16x8 a[2];
#pragma unroll
            for (int fi = 0; fi < 2; ++fi)
                a[fi] = *reinterpret_cast<const bf16x8*>(
                    &As[cur][(32 * w + 16 * fi + t) * LDST + koff]);
#pragma unroll
            for (int fi = 0; fi < 2; ++fi)
#pragma unroll
                for (int fj = 0; fj < 2; ++fj)
                    acc[fi][fj] = __builtin_amdgcn_mfma_f32_16x16x32_bf16(
                        a[fi], bfrag[ks][fj], acc[fi][fj], 0, 0, 0);
        }

        // ---- epilogue: |d| thresholds; transposed store -> contiguous f32x4 ----
        const bool has_diag = (ct == diag_ct);
#pragma unroll
        for (int fj = 0; fj < 2; ++fj) {
            const int orow = strip0 + 16 * fj + t;               // output row (strip side)
#pragma unroll
            for (int fi = 0; fi < 2; ++fi) {
                const int ocol0 = ct * 256 + 32 * w + 16 * fi + 4 * g;  // output col base (panel side)
                float wv[4];
#pragma unroll
                for (int r = 0; r < 4; ++r) {
                    const float d = acc[fi][fj][r];
                    float wt = (fabsf(d) >= 0.97467943f) ? 1.0f
                             : ((fabsf(d) >= 0.70710678f) ? 0.5f : 0.0f);
                    if (has_diag && (ocol0 + r == orow)) wt = 0.0f;
                    rs[fj] += wt;
                    wv[r] = -wt;
                }
                f32x4 st = {wv[0], wv[1], wv[2], wv[3]};
                *reinterpret_cast<f32x4*>(&outb[(size_t)orow * N + ocol0]) = st;
            }
        }

        // ---- write next panel into the other buffer ----
        if (ct + 1 < nct) {
#pragma unroll
            for (int it = 0; it < 8; ++it) {
                int idx = tid + it * 512;
                int r = idx >> 4, q = idx & 15;
                float4 v = pre[it];
                bf16x4 h = {(__bf16)v.x, (__bf16)v.y, (__bf16)v.z, (__bf16)v.w};
                *reinterpret_cast<bf16x4*>(&As[cur ^ 1][r * LDST + q * 4]) = h;
            }
        }
        lds_barrier();
        cur ^= 1;
    }

    // ---- degree: reduce over g via shfl, across 8 waves via LDS ----
    rs[0] += __shfl_xor(rs[0], 16, 64); rs[0] += __shfl_xor(rs[0], 32, 64);
    rs[1] += __shfl_xor(rs[1], 16, 64); rs[1] += __shfl_xor(rs[1], 32, 64);
    if (g == 0) { deg_part[w][t] = rs[0]; deg_part[w][16 + t] = rs[1]; }
    full_barrier();   // drains vmem too: the diag-line store must land before overwrite
    if (tid < 32) {
        float d = 0.f;
#pragma unroll
        for (int ww = 0; ww < 8; ++ww) d += deg_part[ww][tid];
        const int rr = strip0 + tid;
        outb[(size_t)rr * N + rr] = d;   // diagonal = degree
    }
}

extern "C" void kernel_launch(void* const* d_in, const int* in_sizes, int n_in,
                              void* d_out, int out_size, void* d_ws, size_t ws_size,
                              hipStream_t stream) {
    const float* X = (const float*)d_in[0];
    float* out = (float*)d_out;

    const int B = 8;
    const int D = 64;
    const int N = in_sizes[0] / (B * D);   // 2048

    dim3 grid((N / 32) * B);               // 512 blocks, batch = id & 7
    lap_strip_kernel<<<grid, dim3(512), 0, stream>>>(X, out, N);
}